// Round 7
// baseline (482.793 us; speedup 1.0000x reference)
//
#include <hip/hip_runtime.h>
#include <math.h>

#define N_NODES 50000
#define E_RAW   800000
#define E_TOT   850000
#define NEG_SLOPE 0.2f
#define NBC 196   // scan blocks = ceil(50000/256)

typedef __attribute__((ext_vector_type(8))) short short8;
typedef __attribute__((ext_vector_type(4))) float f32x4;

__device__ __forceinline__ float lrelu(float v) {
    return v >= 0.f ? v : NEG_SLOPE * v;
}
__device__ __forceinline__ unsigned short f2bf(float f) {
    union { float f; unsigned u; } v; v.f = f;
    unsigned r = v.u + 0x7FFF + ((v.u >> 16) & 1);
    return (unsigned short)(r >> 16);
}
__device__ __forceinline__ float bf2f(unsigned short h) {
    union { unsigned u; float f; } v; v.u = ((unsigned)h) << 16;
    return v.f;
}

// ---------------------------------------------------------------------------
// CSR build: histogram -> coalesced 3-phase scan -> scatter.
// ---------------------------------------------------------------------------
__global__ __launch_bounds__(256) void k_hist(
    const int* __restrict__ dst, int* __restrict__ counts)
{
    int e = blockIdx.x * 256 + threadIdx.x;
    if (e >= E_TOT) return;
    int d = (e < E_RAW) ? dst[e] : e - E_RAW;
    atomicAdd(&counts[d], 1);
}

__global__ __launch_bounds__(256) void k_scan1(
    const int* __restrict__ counts, int* __restrict__ off, int* __restrict__ bsum)
{
    __shared__ int sh[256];
    int t = threadIdx.x, i = blockIdx.x * 256 + t;
    int c = (i < N_NODES) ? counts[i] : 0;
    sh[t] = c; __syncthreads();
    for (int ofs = 1; ofs < 256; ofs <<= 1) {
        int v = (t >= ofs) ? sh[t - ofs] : 0;
        __syncthreads(); sh[t] += v; __syncthreads();
    }
    if (i < N_NODES) off[i] = sh[t] - c;
    if (t == 255) bsum[blockIdx.x] = sh[255];
}

__global__ __launch_bounds__(256) void k_scan2(int* __restrict__ bsum)
{
    __shared__ int sh[256];
    int t = threadIdx.x;
    int c = (t < NBC) ? bsum[t] : 0;
    sh[t] = c; __syncthreads();
    for (int ofs = 1; ofs < 256; ofs <<= 1) {
        int v = (t >= ofs) ? sh[t - ofs] : 0;
        __syncthreads(); sh[t] += v; __syncthreads();
    }
    if (t < NBC) bsum[t] = sh[t] - c;
}

__global__ __launch_bounds__(256) void k_scan3(
    int* __restrict__ off, const int* __restrict__ bsum)
{
    int i = blockIdx.x * 256 + threadIdx.x;
    if (i < N_NODES) off[i] += bsum[blockIdx.x];
    if (i == 0) off[N_NODES] = E_TOT;
}

__global__ __launch_bounds__(256) void k_scatter(
    const int* __restrict__ src, const int* __restrict__ dst,
    const int* __restrict__ off, int* __restrict__ cursor,
    int* __restrict__ esrc)
{
    int e = blockIdx.x * 256 + threadIdx.x;
    if (e >= E_TOT) return;
    int s, d;
    if (e < E_RAW) { s = src[e]; d = dst[e]; } else { s = e - E_RAW; d = s; }
    int pos = off[d] + atomicAdd(&cursor[d], 1);
    esrc[pos] = s;
}

// ---------------------------------------------------------------------------
// Weight prep into MFMA B-fragment order (bf16), plain k axis.
// ---------------------------------------------------------------------------
__global__ __launch_bounds__(256) void k_prepw1(
    const float* __restrict__ W1, unsigned short* __restrict__ Wf1)
{
    int idx = blockIdx.x * 256 + threadIdx.x;       // 0..8191
    int lane = idx & 63, kb = (idx >> 6) & 7, nb = idx >> 9;
    int c = nb * 16 + (lane & 15);
    int k0 = kb * 32 + ((lane >> 4) & 3) * 8;
    short8 pk;
#pragma unroll
    for (int j = 0; j < 8; ++j)
        pk[j] = (short)f2bf(W1[(k0 + j) * 256 + c]);
    *(short8*)&Wf1[idx * 8] = pk;
}

__global__ __launch_bounds__(256) void k_prepw2(
    const float* __restrict__ W2, unsigned short* __restrict__ Wf2)
{
    int idx = blockIdx.x * 256 + threadIdx.x;       // 0..2047
    int lane = idx & 63, kb = (idx >> 6) & 7, nb = idx >> 9;
    int c = nb * 16 + (lane & 15);
    int k0 = kb * 32 + ((lane >> 4) & 3) * 8;
    short8 pk;
#pragma unroll
    for (int j = 0; j < 8; ++j)
        pk[j] = (short)f2bf(W2[(k0 + j) * 64 + c]);
    *(short8*)&Wf2[idx * 8] = pk;
}

// ---------------------------------------------------------------------------
// GEMM1: h1 = x @ W1, MFMA 16x16x32. 3125 blocks x 4 waves, 16 rows/block,
// wave w = head w. Register double-buffer; plain h1b; fused att-dot epilogue.
// ---------------------------------------------------------------------------
__global__ __launch_bounds__(256) void k_gemm1(
    const float* __restrict__ x, const unsigned short* __restrict__ Wf1,
    const float* __restrict__ att_src, const float* __restrict__ att_dst,
    unsigned short* __restrict__ h1b, float* __restrict__ as1, float* __restrict__ ad1)
{
    const int t = threadIdx.x;
    const int lane = t & 63;
    const int w = t >> 6;
    const int rbase = blockIdx.x * 16;
    const int q  = lane & 15;
    const int kg = lane >> 4;
    const int rowA = rbase + q;

    f32x4 acc[4];
#pragma unroll
    for (int nb = 0; nb < 4; ++nb) acc[nb] = (f32x4){0.f, 0.f, 0.f, 0.f};

    short8 b[2][4];
    float4 a0, a1, a0n, a1n;
    {
        const float* ap = &x[rowA * 256 + kg * 8];
        a0 = *(const float4*)ap;
        a1 = *(const float4*)(ap + 4);
#pragma unroll
        for (int nb = 0; nb < 4; ++nb)
            b[0][nb] = *(const short8*)&Wf1[(((w * 4 + nb) * 8 + 0) * 64 + lane) * 8];
    }
#pragma unroll
    for (int kb = 0; kb < 8; ++kb) {
        if (kb < 7) {
            const float* ap = &x[rowA * 256 + (kb + 1) * 32 + kg * 8];
            a0n = *(const float4*)ap;
            a1n = *(const float4*)(ap + 4);
#pragma unroll
            for (int nb = 0; nb < 4; ++nb)
                b[(kb + 1) & 1][nb] =
                    *(const short8*)&Wf1[(((w * 4 + nb) * 8 + kb + 1) * 64 + lane) * 8];
        }
        short8 af;
        af[0] = (short)f2bf(a0.x); af[1] = (short)f2bf(a0.y);
        af[2] = (short)f2bf(a0.z); af[3] = (short)f2bf(a0.w);
        af[4] = (short)f2bf(a1.x); af[5] = (short)f2bf(a1.y);
        af[6] = (short)f2bf(a1.z); af[7] = (short)f2bf(a1.w);
#pragma unroll
        for (int nb = 0; nb < 4; ++nb)
            acc[nb] = __builtin_amdgcn_mfma_f32_16x16x32_bf16(af, b[kb & 1][nb], acc[nb], 0, 0, 0);
        if (kb < 7) { a0 = a0n; a1 = a1n; }
    }

#pragma unroll
    for (int reg = 0; reg < 4; ++reg) {
        int n = rbase + kg * 4 + reg;
#pragma unroll
        for (int nb = 0; nb < 4; ++nb)
            h1b[n * 256 + (w * 4 + nb) * 16 + q] = f2bf(acc[nb][reg]);
    }
    float asv[4], adv[4];
#pragma unroll
    for (int nb = 0; nb < 4; ++nb) {
        int col = (w * 4 + nb) * 16 + q;
        asv[nb] = att_src[col];
        adv[nb] = att_dst[col];
    }
#pragma unroll
    for (int reg = 0; reg < 4; ++reg) {
        float s = acc[0][reg]*asv[0] + acc[1][reg]*asv[1] + acc[2][reg]*asv[2] + acc[3][reg]*asv[3];
        float d = acc[0][reg]*adv[0] + acc[1][reg]*adv[1] + acc[2][reg]*adv[2] + acc[3][reg]*adv[3];
#pragma unroll
        for (int ofs = 1; ofs < 16; ofs <<= 1) {
            s += __shfl_xor(s, ofs);
            d += __shfl_xor(d, ofs);
        }
        if (q == 0) {
            int n = rbase + kg * 4 + reg;
            as1[n * 4 + w] = s;
            ad1[n * 4 + w] = d;
        }
    }
}

// ---------------------------------------------------------------------------
// alpha1: normalized softmax weights per edge, bf16, SoA BY HEAD:
// aw1h[head*E_TOT + e]. (SoA so the gather's per-head stream is 1.7 MB,
// not the whole 6.8 MB AoS.)
// ---------------------------------------------------------------------------
__global__ __launch_bounds__(256) void k_alpha1(
    const int* __restrict__ esrc, const int* __restrict__ off,
    const float* __restrict__ as1, const float* __restrict__ ad1,
    unsigned short* __restrict__ aw1h)
{
    int d    = (blockIdx.x * 256 + threadIdx.x) >> 6;
    int lane = threadIdx.x & 63;
    if (d >= N_NODES) return;
    const int head = lane & 3;
    const int ei   = lane >> 2;                     // 16 edge slots
    unsigned short* awp = aw1h + head * E_TOT;
    const float adv = ad1[d * 4 + head];
    const int e0 = off[d], e1 = off[d + 1];
    float dn = 0.f;
    for (int e = e0 + ei; e < e1; e += 16) {
        int s = esrc[e];
        float wv = __expf(lrelu(as1[s * 4 + head] + adv));
        unsigned short r = f2bf(wv);
        dn += bf2f(r);
        awp[e] = r;
    }
#pragma unroll
    for (int ofs = 4; ofs < 64; ofs <<= 1) dn += __shfl_xor(dn, ofs);
    const float inv = 1.f / (dn + 1e-16f);
    for (int e = e0 + ei; e < e1; e += 16) {
        awp[e] = f2bf(bf2f(awp[e]) * inv);
    }
}

// ---------------------------------------------------------------------------
// gather1: column-partitioned weighted gather + bias + ELU.
// Grid 100000 = 12500 dst-chunks x 8 col-groups; cg = blockIdx%8 pins each
// 32-col slice (3.2 MB) to one XCD's L2 under round-robin dispatch.
// esrc/aw loads are NON-TEMPORAL (evict-first) so the streams don't evict
// the resident h1b slice (round-6 failure mode). Wave per dst.
// ---------------------------------------------------------------------------
__global__ __launch_bounds__(256) void k_gather1(
    const int* __restrict__ esrc, const int* __restrict__ off,
    const unsigned short* __restrict__ aw1h,
    const unsigned short* __restrict__ h1b, const float* __restrict__ b1,
    unsigned short* __restrict__ hmid)
{
    const int bid = blockIdx.x;
    const int cg  = bid & 7;
    const int t = threadIdx.x;
    const int w = t >> 6;
    const int lane = t & 63;
    const int d = (bid >> 3) * 4 + w;               // 12500*4 = 50000 exact
    const int k  = lane & 15;
    const int ep = lane >> 4;
    const unsigned short* awp = aw1h + (cg >> 1) * E_TOT;
    const int e0 = off[d], e1 = off[d + 1];
    const unsigned short* hb = h1b + cg * 32 + k * 2;
    float a0 = 0.f, a1 = 0.f;
    int e = e0 + ep;
    for (; e + 4 < e1; e += 8) {
        int sA = __builtin_nontemporal_load(&esrc[e]);
        int sB = __builtin_nontemporal_load(&esrc[e + 4]);
        float wA = bf2f(__builtin_nontemporal_load(&awp[e]));
        float wB = bf2f(__builtin_nontemporal_load(&awp[e + 4]));
        unsigned uA = *(const unsigned*)(hb + sA * 256);
        unsigned uB = *(const unsigned*)(hb + sB * 256);
        a0 = fmaf(wA, bf2f((unsigned short)uA), fmaf(wB, bf2f((unsigned short)uB), a0));
        a1 = fmaf(wA, bf2f((unsigned short)(uA >> 16)), fmaf(wB, bf2f((unsigned short)(uB >> 16)), a1));
    }
    if (e < e1) {
        int sA = __builtin_nontemporal_load(&esrc[e]);
        float wA = bf2f(__builtin_nontemporal_load(&awp[e]));
        unsigned uA = *(const unsigned*)(hb + sA * 256);
        a0 = fmaf(wA, bf2f((unsigned short)uA), a0);
        a1 = fmaf(wA, bf2f((unsigned short)(uA >> 16)), a1);
    }
    a0 += __shfl_xor(a0, 16); a0 += __shfl_xor(a0, 32);
    a1 += __shfl_xor(a1, 16); a1 += __shfl_xor(a1, 32);
    if (ep == 0) {
        int col = cg * 32 + k * 2;
        float v0 = a0 + b1[col];
        float v1 = a1 + b1[col + 1];
        v0 = v0 > 0.f ? v0 : expm1f(v0);
        v1 = v1 > 0.f ? v1 : expm1f(v1);
        unsigned pk = (unsigned)f2bf(v0) | ((unsigned)f2bf(v1) << 16);
        *(unsigned*)&hmid[d * 256 + col] = pk;
    }
}

// ---------------------------------------------------------------------------
// GEMM2: h2 = hmid @ W2. Plain layouts; register double-buffer; fused att2.
// ---------------------------------------------------------------------------
__global__ __launch_bounds__(256) void k_gemm2(
    const unsigned short* __restrict__ hmid, const unsigned short* __restrict__ Wf2,
    const float* __restrict__ att_src, const float* __restrict__ att_dst,
    unsigned short* __restrict__ h2b, float* __restrict__ as2, float* __restrict__ ad2)
{
    const int t = threadIdx.x;
    const int lane = t & 63;
    const int w = t >> 6;
    const int rbase = blockIdx.x * 64 + w * 16;
    const int q  = lane & 15;
    const int kg = lane >> 4;
    const int rowA = rbase + q;
    const int rA = rowA < N_NODES ? rowA : N_NODES - 1;

    f32x4 acc[4];
#pragma unroll
    for (int nb = 0; nb < 4; ++nb) acc[nb] = (f32x4){0.f, 0.f, 0.f, 0.f};

    short8 b[2][4];
    short8 af, afn;
    af = *(const short8*)&hmid[rA * 256 + kg * 8];
#pragma unroll
    for (int nb = 0; nb < 4; ++nb)
        b[0][nb] = *(const short8*)&Wf2[((nb * 8 + 0) * 64 + lane) * 8];
#pragma unroll
    for (int kb = 0; kb < 8; ++kb) {
        if (kb < 7) {
            afn = *(const short8*)&hmid[rA * 256 + (kb + 1) * 32 + kg * 8];
#pragma unroll
            for (int nb = 0; nb < 4; ++nb)
                b[(kb + 1) & 1][nb] = *(const short8*)&Wf2[((nb * 8 + kb + 1) * 64 + lane) * 8];
        }
#pragma unroll
        for (int nb = 0; nb < 4; ++nb)
            acc[nb] = __builtin_amdgcn_mfma_f32_16x16x32_bf16(af, b[kb & 1][nb], acc[nb], 0, 0, 0);
        if (kb < 7) af = afn;
    }

    float asv[4], adv[4];
#pragma unroll
    for (int nb = 0; nb < 4; ++nb) {
        int col = nb * 16 + q;
        asv[nb] = att_src[col];
        adv[nb] = att_dst[col];
    }
#pragma unroll
    for (int reg = 0; reg < 4; ++reg) {
        int n = rbase + kg * 4 + reg;
        bool ok = n < N_NODES;
        if (ok) {
#pragma unroll
            for (int nb = 0; nb < 4; ++nb)
                h2b[n * 64 + nb * 16 + q] = f2bf(acc[nb][reg]);
        }
        float s = acc[0][reg]*asv[0] + acc[1][reg]*asv[1] + acc[2][reg]*asv[2] + acc[3][reg]*asv[3];
        float d = acc[0][reg]*adv[0] + acc[1][reg]*adv[1] + acc[2][reg]*adv[2] + acc[3][reg]*adv[3];
#pragma unroll
        for (int ofs = 1; ofs < 16; ofs <<= 1) {
            s += __shfl_xor(s, ofs);
            d += __shfl_xor(d, ofs);
        }
        if (ok && q == 0) { as2[n] = s; ad2[n] = d; }
    }
}

// ---------------------------------------------------------------------------
// alpha2: normalized weights for layer 2 (1 head). Wave per dst, lane = edge.
// ---------------------------------------------------------------------------
__global__ __launch_bounds__(256) void k_alpha2(
    const int* __restrict__ esrc, const int* __restrict__ off,
    const float* __restrict__ as2, const float* __restrict__ ad2,
    unsigned short* __restrict__ aw2)
{
    int d    = (blockIdx.x * 256 + threadIdx.x) >> 6;
    int lane = threadIdx.x & 63;
    if (d >= N_NODES) return;
    const float adv = ad2[d];
    const int e0 = off[d], e1 = off[d + 1];
    float dn = 0.f;
    for (int e = e0 + lane; e < e1; e += 64) {
        int s = esrc[e];
        float wv = __expf(lrelu(as2[s] + adv));
        unsigned short r = f2bf(wv);
        dn += bf2f(r);
        aw2[e] = r;
    }
#pragma unroll
    for (int ofs = 1; ofs < 64; ofs <<= 1) dn += __shfl_xor(dn, ofs);
    const float inv = 1.f / (dn + 1e-16f);
    for (int e = e0 + lane; e < e1; e += 64) {
        aw2[e] = f2bf(bf2f(aw2[e]) * inv);
    }
}

// ---------------------------------------------------------------------------
// gather2: full-row (h2b only 6.4 MB; 8-XCD stream floor ~51 MB). Wave per
// dst, lane = col; precomputed aw2, nt loads on esrc/aw2; 4x unroll.
// ---------------------------------------------------------------------------
__global__ __launch_bounds__(256) void k_gather2(
    const int* __restrict__ esrc, const int* __restrict__ off,
    const unsigned short* __restrict__ aw2,
    const unsigned short* __restrict__ h2b, const float* __restrict__ b2,
    float* __restrict__ out)
{
    int d    = (blockIdx.x * 256 + threadIdx.x) >> 6;   // 12500*4 = 50000 exact
    int lane = threadIdx.x & 63;
    const int e0 = off[d], e1 = off[d + 1];
    float acc = 0.f;
    int e = e0;
    for (; e + 3 < e1; e += 4) {
        int s0 = __builtin_nontemporal_load(&esrc[e]);
        int s1 = __builtin_nontemporal_load(&esrc[e + 1]);
        int s2 = __builtin_nontemporal_load(&esrc[e + 2]);
        int s3 = __builtin_nontemporal_load(&esrc[e + 3]);
        float w0 = bf2f(__builtin_nontemporal_load(&aw2[e]));
        float w1 = bf2f(__builtin_nontemporal_load(&aw2[e + 1]));
        float w2 = bf2f(__builtin_nontemporal_load(&aw2[e + 2]));
        float w3 = bf2f(__builtin_nontemporal_load(&aw2[e + 3]));
        float v0 = bf2f(h2b[s0 * 64 + lane]);
        float v1 = bf2f(h2b[s1 * 64 + lane]);
        float v2 = bf2f(h2b[s2 * 64 + lane]);
        float v3 = bf2f(h2b[s3 * 64 + lane]);
        acc = fmaf(w0, v0, fmaf(w1, v1, fmaf(w2, v2, fmaf(w3, v3, acc))));
    }
    for (; e < e1; ++e) {
        int s0 = __builtin_nontemporal_load(&esrc[e]);
        float w0 = bf2f(__builtin_nontemporal_load(&aw2[e]));
        acc = fmaf(w0, bf2f(h2b[s0 * 64 + lane]), acc);
    }
    out[d * 64 + lane] = acc + b2[lane];
}

// ---------------------------------------------------------------------------
// Workspace layout (bytes), total ~65.9 MB (same as round 6; aw1 now SoA).
// ---------------------------------------------------------------------------
extern "C" void kernel_launch(void* const* d_in, const int* in_sizes, int n_in,
                              void* d_out, int out_size, void* d_ws, size_t ws_size,
                              hipStream_t stream)
{
    const float* x        = (const float*)d_in[0];
    const int*   ei       = (const int*)d_in[1];
    const float* W1       = (const float*)d_in[2];
    const float* att_src1 = (const float*)d_in[3];
    const float* att_dst1 = (const float*)d_in[4];
    const float* b1       = (const float*)d_in[5];
    const float* W2       = (const float*)d_in[6];
    const float* att_src2 = (const float*)d_in[7];
    const float* att_dst2 = (const float*)d_in[8];
    const float* b2       = (const float*)d_in[9];
    const int* src = ei;
    const int* dst = ei + E_RAW;
    float* out = (float*)d_out;

    char* ws = (char*)d_ws;
    int*            counts = (int*)(ws + 0);
    int*            cursor = (int*)(ws + 200000);
    int*            off    = (int*)(ws + 400000);
    int*            bsum   = (int*)(ws + 600064);
    float*          as1    = (float*)(ws + 600896);
    float*          ad1    = (float*)(ws + 1400896);
    float*          as2    = (float*)(ws + 2200896);
    float*          ad2    = (float*)(ws + 2400896);
    int*            esrc   = (int*)(ws + 2600896);
    unsigned short* Wf1    = (unsigned short*)(ws + 6000896);
    unsigned short* Wf2    = (unsigned short*)(ws + 6131968);
    unsigned short* aw1h   = (unsigned short*)(ws + 6164736);   // 4 x 1.7 MB SoA
    unsigned short* aw2    = (unsigned short*)(ws + 12964736);
    unsigned short* h1b    = (unsigned short*)(ws + 14664736);
    unsigned short* h2b    = (unsigned short*)(ws + 14664736);  // reuses h1b
    unsigned short* hmid   = (unsigned short*)(ws + 40264736);

    hipMemsetAsync(ws, 0, 400000, stream);      // counts + cursor

    const int EB = (E_TOT + 255) / 256;
    k_prepw1 <<<32, 256, 0, stream>>>(W1, Wf1);
    k_prepw2 <<<8, 256, 0, stream>>>(W2, Wf2);
    k_hist   <<<EB, 256, 0, stream>>>(dst, counts);
    k_scan1  <<<NBC, 256, 0, stream>>>(counts, off, bsum);
    k_scan2  <<<1, 256, 0, stream>>>(bsum);
    k_scan3  <<<NBC, 256, 0, stream>>>(off, bsum);
    k_scatter<<<EB, 256, 0, stream>>>(src, dst, off, cursor, esrc);

    k_gemm1  <<<3125, 256, 0, stream>>>(x, Wf1, att_src1, att_dst1, h1b, as1, ad1);
    k_alpha1 <<<12500, 256, 0, stream>>>(esrc, off, as1, ad1, aw1h);
    k_gather1<<<100000, 256, 0, stream>>>(esrc, off, aw1h, h1b, b1, hmid);
    k_gemm2  <<<782, 256, 0, stream>>>(hmid, Wf2, att_src2, att_dst2, h2b, as2, ad2);
    k_alpha2 <<<12500, 256, 0, stream>>>(esrc, off, as2, ad2, aw2);
    k_gather2<<<12500, 256, 0, stream>>>(esrc, off, aw2, h2b, b2, out);
}

// Round 8
// 255.224 us; speedup vs baseline: 1.8916x; 1.8916x over previous
//
#include <hip/hip_runtime.h>
#include <math.h>

#define N_NODES 50000
#define E_RAW   800000
#define E_TOT   850000
#define NEG_SLOPE 0.2f
#define NBC 196   // scan blocks = ceil(50000/256)

typedef __attribute__((ext_vector_type(8))) short short8;
typedef __attribute__((ext_vector_type(4))) float f32x4;

__device__ __forceinline__ float lrelu(float v) {
    return v >= 0.f ? v : NEG_SLOPE * v;
}
__device__ __forceinline__ unsigned short f2bf(float f) {
    union { float f; unsigned u; } v; v.f = f;
    unsigned r = v.u + 0x7FFF + ((v.u >> 16) & 1);
    return (unsigned short)(r >> 16);
}
__device__ __forceinline__ float bf2f(unsigned short h) {
    union { unsigned u; float f; } v; v.u = ((unsigned)h) << 16;
    return v.f;
}
// h1b/hmid position p holds column C1(p) (16x16 transpose, self-inverse)
__device__ __forceinline__ int C1(int p) { return (p & 15) * 16 + (p >> 4); }
// h2b position p holds column C2(p)
__device__ __forceinline__ int C2(int p) { return (p & 3) * 16 + (p >> 2); }

// ---------------------------------------------------------------------------
// CSR build: histogram -> coalesced 3-phase scan -> scatter (uint16 esrc).
// ---------------------------------------------------------------------------
__global__ __launch_bounds__(256) void k_hist(
    const int* __restrict__ dst, int* __restrict__ counts)
{
    int e = blockIdx.x * 256 + threadIdx.x;
    if (e >= E_TOT) return;
    int d = (e < E_RAW) ? dst[e] : e - E_RAW;
    atomicAdd(&counts[d], 1);
}

__global__ __launch_bounds__(256) void k_scan1(
    const int* __restrict__ counts, int* __restrict__ off, int* __restrict__ bsum)
{
    __shared__ int sh[256];
    int t = threadIdx.x, i = blockIdx.x * 256 + t;
    int c = (i < N_NODES) ? counts[i] : 0;
    sh[t] = c; __syncthreads();
    for (int ofs = 1; ofs < 256; ofs <<= 1) {
        int v = (t >= ofs) ? sh[t - ofs] : 0;
        __syncthreads(); sh[t] += v; __syncthreads();
    }
    if (i < N_NODES) off[i] = sh[t] - c;
    if (t == 255) bsum[blockIdx.x] = sh[255];
}

__global__ __launch_bounds__(256) void k_scan2(int* __restrict__ bsum)
{
    __shared__ int sh[256];
    int t = threadIdx.x;
    int c = (t < NBC) ? bsum[t] : 0;
    sh[t] = c; __syncthreads();
    for (int ofs = 1; ofs < 256; ofs <<= 1) {
        int v = (t >= ofs) ? sh[t - ofs] : 0;
        __syncthreads(); sh[t] += v; __syncthreads();
    }
    if (t < NBC) bsum[t] = sh[t] - c;
}

__global__ __launch_bounds__(256) void k_scan3(
    int* __restrict__ off, const int* __restrict__ bsum)
{
    int i = blockIdx.x * 256 + threadIdx.x;
    if (i < N_NODES) off[i] += bsum[blockIdx.x];
    if (i == 0) off[N_NODES] = E_TOT;
}

__global__ __launch_bounds__(256) void k_scatter(
    const int* __restrict__ src, const int* __restrict__ dst,
    const int* __restrict__ off, int* __restrict__ cursor,
    unsigned short* __restrict__ esrc)
{
    int e = blockIdx.x * 256 + threadIdx.x;
    if (e >= E_TOT) return;
    int s, d;
    if (e < E_RAW) { s = src[e]; d = dst[e]; } else { s = e - E_RAW; d = s; }
    int pos = off[d] + atomicAdd(&cursor[d], 1);
    esrc[pos] = (unsigned short)s;
}

// ---------------------------------------------------------------------------
// Weight prep (merged): Wf1 plain-k frags (idx<8192), Wf2 frags with k-axis
// pre-permuted by C1 (hmid is stored C1-permuted).
// ---------------------------------------------------------------------------
__global__ __launch_bounds__(256) void k_prepw(
    const float* __restrict__ W1, const float* __restrict__ W2,
    unsigned short* __restrict__ Wf1, unsigned short* __restrict__ Wf2)
{
    int idx = blockIdx.x * 256 + threadIdx.x;       // 0..10239
    if (idx < 8192) {
        int lane = idx & 63, kb = (idx >> 6) & 7, nb = idx >> 9;
        int c = nb * 16 + (lane & 15);
        int k0 = kb * 32 + ((lane >> 4) & 3) * 8;
        short8 pk;
#pragma unroll
        for (int j = 0; j < 8; ++j)
            pk[j] = (short)f2bf(W1[(k0 + j) * 256 + c]);
        *(short8*)&Wf1[idx * 8] = pk;
    } else if (idx < 10240) {
        int i2 = idx - 8192;                        // 0..2047
        int lane = i2 & 63, kb = (i2 >> 6) & 7, nb = i2 >> 9;
        int c = nb * 16 + (lane & 15);
        int k0 = kb * 32 + ((lane >> 4) & 3) * 8;
        short8 pk;
#pragma unroll
        for (int j = 0; j < 8; ++j)
            pk[j] = (short)f2bf(W2[C1(k0 + j) * 64 + c]);
        *(short8*)&Wf2[i2 * 8] = pk;
    }
}

// ---------------------------------------------------------------------------
// GEMM1: h1 = x @ W1, MFMA 16x16x32. 3125 blocks x 4 waves, 16 rows/block,
// wave w = head w. Register double-buffer. h1b stored C1-PERMUTED:
// position p = q*16 + w*4 + nb holds col (w*4+nb)*16+q  ->  8B ushort4 store.
// Fused att-dot epilogue.
// ---------------------------------------------------------------------------
__global__ __launch_bounds__(256) void k_gemm1(
    const float* __restrict__ x, const unsigned short* __restrict__ Wf1,
    const float* __restrict__ att_src, const float* __restrict__ att_dst,
    unsigned short* __restrict__ h1b, float* __restrict__ as1, float* __restrict__ ad1)
{
    const int t = threadIdx.x;
    const int lane = t & 63;
    const int w = t >> 6;
    const int rbase = blockIdx.x * 16;
    const int q  = lane & 15;
    const int kg = lane >> 4;
    const int rowA = rbase + q;

    f32x4 acc[4];
#pragma unroll
    for (int nb = 0; nb < 4; ++nb) acc[nb] = (f32x4){0.f, 0.f, 0.f, 0.f};

    short8 b[2][4];
    float4 a0, a1, a0n, a1n;
    {
        const float* ap = &x[rowA * 256 + kg * 8];
        a0 = *(const float4*)ap;
        a1 = *(const float4*)(ap + 4);
#pragma unroll
        for (int nb = 0; nb < 4; ++nb)
            b[0][nb] = *(const short8*)&Wf1[(((w * 4 + nb) * 8 + 0) * 64 + lane) * 8];
    }
#pragma unroll
    for (int kb = 0; kb < 8; ++kb) {
        if (kb < 7) {
            const float* ap = &x[rowA * 256 + (kb + 1) * 32 + kg * 8];
            a0n = *(const float4*)ap;
            a1n = *(const float4*)(ap + 4);
#pragma unroll
            for (int nb = 0; nb < 4; ++nb)
                b[(kb + 1) & 1][nb] =
                    *(const short8*)&Wf1[(((w * 4 + nb) * 8 + kb + 1) * 64 + lane) * 8];
        }
        short8 af;
        af[0] = (short)f2bf(a0.x); af[1] = (short)f2bf(a0.y);
        af[2] = (short)f2bf(a0.z); af[3] = (short)f2bf(a0.w);
        af[4] = (short)f2bf(a1.x); af[5] = (short)f2bf(a1.y);
        af[6] = (short)f2bf(a1.z); af[7] = (short)f2bf(a1.w);
#pragma unroll
        for (int nb = 0; nb < 4; ++nb)
            acc[nb] = __builtin_amdgcn_mfma_f32_16x16x32_bf16(af, b[kb & 1][nb], acc[nb], 0, 0, 0);
        if (kb < 7) { a0 = a0n; a1 = a1n; }
    }

#pragma unroll
    for (int reg = 0; reg < 4; ++reg) {
        int n = rbase + kg * 4 + reg;
        ushort4 pk;
        pk.x = f2bf(acc[0][reg]); pk.y = f2bf(acc[1][reg]);
        pk.z = f2bf(acc[2][reg]); pk.w = f2bf(acc[3][reg]);
        *(ushort4*)&h1b[n * 256 + q * 16 + w * 4] = pk;   // permuted, 8B
    }
    float asv[4], adv[4];
#pragma unroll
    for (int nb = 0; nb < 4; ++nb) {
        int col = (w * 4 + nb) * 16 + q;
        asv[nb] = att_src[col];
        adv[nb] = att_dst[col];
    }
#pragma unroll
    for (int reg = 0; reg < 4; ++reg) {
        float s = acc[0][reg]*asv[0] + acc[1][reg]*asv[1] + acc[2][reg]*asv[2] + acc[3][reg]*asv[3];
        float d = acc[0][reg]*adv[0] + acc[1][reg]*adv[1] + acc[2][reg]*adv[2] + acc[3][reg]*adv[3];
#pragma unroll
        for (int ofs = 1; ofs < 16; ofs <<= 1) {
            s += __shfl_xor(s, ofs);
            d += __shfl_xor(d, ofs);
        }
        if (q == 0) {
            int n = rbase + kg * 4 + reg;
            as1[n * 4 + w] = s;
            ad1[n * 4 + w] = d;
        }
    }
}

// ---------------------------------------------------------------------------
// gather1: fused softmax + aggregate + bias + ELU, full-row form.
// ONE DST PER 32-LANE HALF-WAVE: lane j in [0,32) owns positions j*8..+8
// (short8 = 16B/lane, 32 lanes = full 512B row). Position p=j*8+i has
// head 2*(j&1)+(i>>2), so lane needs exactly 2 heads -> float2 as1/ad1
// loads. Every lane accumulates the full denominators for its 2 heads
// (all lanes see all edges) -> ZERO cross-lane reduction. 4x edge unroll;
// 2 dst/wave + 4-deep unroll = 8 row-reads in flight per wave.
// ---------------------------------------------------------------------------
__global__ __launch_bounds__(256) void k_gather1(
    const unsigned short* __restrict__ esrc, const int* __restrict__ off,
    const float* __restrict__ as1, const float* __restrict__ ad1,
    const unsigned short* __restrict__ h1b, const float* __restrict__ b1,
    unsigned short* __restrict__ hmid)
{
    const int t = threadIdx.x;
    const int w = t >> 6;
    const int lane = t & 63;
    const int h = lane >> 5;                        // half-wave
    const int j = lane & 31;                        // col-lane
    const int d = blockIdx.x * 8 + w * 2 + h;       // 6250*8 = 50000 exact
    const int hA = 2 * (j & 1);                     // heads hA, hA+1
    const float2 advv = *(const float2*)&ad1[d * 4 + hA];
    const int e0 = off[d], e1 = off[d + 1];
    const unsigned short* hb = h1b + j * 8;

    float acc[8];
#pragma unroll
    for (int i = 0; i < 8; ++i) acc[i] = 0.f;
    float dnA = 0.f, dnB = 0.f;

    int e = e0;
    for (; e + 3 < e1; e += 4) {
        int s0 = esrc[e], s1 = esrc[e + 1], s2 = esrc[e + 2], s3 = esrc[e + 3];
        float2 q0 = *(const float2*)&as1[s0 * 4 + hA];
        float2 q1 = *(const float2*)&as1[s1 * 4 + hA];
        float2 q2 = *(const float2*)&as1[s2 * 4 + hA];
        float2 q3 = *(const float2*)&as1[s3 * 4 + hA];
        short8 u0 = *(const short8*)(hb + s0 * 256);
        short8 u1 = *(const short8*)(hb + s1 * 256);
        short8 u2 = *(const short8*)(hb + s2 * 256);
        short8 u3 = *(const short8*)(hb + s3 * 256);
        float wA0 = __expf(lrelu(q0.x + advv.x));
        float wB0 = __expf(lrelu(q0.y + advv.y));
        float wA1 = __expf(lrelu(q1.x + advv.x));
        float wB1 = __expf(lrelu(q1.y + advv.y));
        float wA2 = __expf(lrelu(q2.x + advv.x));
        float wB2 = __expf(lrelu(q2.y + advv.y));
        float wA3 = __expf(lrelu(q3.x + advv.x));
        float wB3 = __expf(lrelu(q3.y + advv.y));
        dnA += (wA0 + wA1) + (wA2 + wA3);
        dnB += (wB0 + wB1) + (wB2 + wB3);
#pragma unroll
        for (int i = 0; i < 4; ++i) {
            acc[i] = fmaf(wA0, bf2f((unsigned short)u0[i]),
                     fmaf(wA1, bf2f((unsigned short)u1[i]),
                     fmaf(wA2, bf2f((unsigned short)u2[i]),
                     fmaf(wA3, bf2f((unsigned short)u3[i]), acc[i]))));
            acc[4 + i] = fmaf(wB0, bf2f((unsigned short)u0[4 + i]),
                         fmaf(wB1, bf2f((unsigned short)u1[4 + i]),
                         fmaf(wB2, bf2f((unsigned short)u2[4 + i]),
                         fmaf(wB3, bf2f((unsigned short)u3[4 + i]), acc[4 + i]))));
        }
    }
    for (; e < e1; ++e) {
        int s0 = esrc[e];
        float2 q0 = *(const float2*)&as1[s0 * 4 + hA];
        short8 u0 = *(const short8*)(hb + s0 * 256);
        float wA0 = __expf(lrelu(q0.x + advv.x));
        float wB0 = __expf(lrelu(q0.y + advv.y));
        dnA += wA0; dnB += wB0;
#pragma unroll
        for (int i = 0; i < 4; ++i) {
            acc[i]     = fmaf(wA0, bf2f((unsigned short)u0[i]), acc[i]);
            acc[4 + i] = fmaf(wB0, bf2f((unsigned short)u0[4 + i]), acc[4 + i]);
        }
    }
    const float invA = 1.f / (dnA + 1e-16f);
    const float invB = 1.f / (dnB + 1e-16f);
    short8 pk;
#pragma unroll
    for (int i = 0; i < 8; ++i) {
        float v = acc[i] * (i < 4 ? invA : invB) + b1[C1(j * 8 + i)];
        v = v > 0.f ? v : expm1f(v);
        pk[i] = (short)f2bf(v);
    }
    *(short8*)&hmid[d * 256 + j * 8] = pk;          // permuted, 16B
}

// ---------------------------------------------------------------------------
// GEMM2: h2 = hmid @ W2 (hmid C1-permuted; Wf2 compensates). Register
// double-buffer; h2b stored C2-permuted (ushort4 8B); fused att2 epilogue.
// ---------------------------------------------------------------------------
__global__ __launch_bounds__(256) void k_gemm2(
    const unsigned short* __restrict__ hmid, const unsigned short* __restrict__ Wf2,
    const float* __restrict__ att_src, const float* __restrict__ att_dst,
    unsigned short* __restrict__ h2b, float* __restrict__ as2, float* __restrict__ ad2)
{
    const int t = threadIdx.x;
    const int lane = t & 63;
    const int w = t >> 6;
    const int rbase = blockIdx.x * 64 + w * 16;
    const int q  = lane & 15;
    const int kg = lane >> 4;
    const int rowA = rbase + q;
    const int rA = rowA < N_NODES ? rowA : N_NODES - 1;

    f32x4 acc[4];
#pragma unroll
    for (int nb = 0; nb < 4; ++nb) acc[nb] = (f32x4){0.f, 0.f, 0.f, 0.f};

    short8 b[2][4];
    short8 af, afn;
    af = *(const short8*)&hmid[rA * 256 + kg * 8];
#pragma unroll
    for (int nb = 0; nb < 4; ++nb)
        b[0][nb] = *(const short8*)&Wf2[((nb * 8 + 0) * 64 + lane) * 8];
#pragma unroll
    for (int kb = 0; kb < 8; ++kb) {
        if (kb < 7) {
            afn = *(const short8*)&hmid[rA * 256 + (kb + 1) * 32 + kg * 8];
#pragma unroll
            for (int nb = 0; nb < 4; ++nb)
                b[(kb + 1) & 1][nb] = *(const short8*)&Wf2[((nb * 8 + kb + 1) * 64 + lane) * 8];
        }
#pragma unroll
        for (int nb = 0; nb < 4; ++nb)
            acc[nb] = __builtin_amdgcn_mfma_f32_16x16x32_bf16(af, b[kb & 1][nb], acc[nb], 0, 0, 0);
        if (kb < 7) af = afn;
    }

    float asv[4], adv[4];
#pragma unroll
    for (int nb = 0; nb < 4; ++nb) {
        int col = nb * 16 + q;
        asv[nb] = att_src[col];
        adv[nb] = att_dst[col];
    }
#pragma unroll
    for (int reg = 0; reg < 4; ++reg) {
        int n = rbase + kg * 4 + reg;
        bool ok = n < N_NODES;
        if (ok) {
            ushort4 pk;
            pk.x = f2bf(acc[0][reg]); pk.y = f2bf(acc[1][reg]);
            pk.z = f2bf(acc[2][reg]); pk.w = f2bf(acc[3][reg]);
            *(ushort4*)&h2b[n * 64 + q * 4] = pk;   // position q*4+nb = col nb*16+q
        }
        float s = acc[0][reg]*asv[0] + acc[1][reg]*asv[1] + acc[2][reg]*asv[2] + acc[3][reg]*asv[3];
        float d = acc[0][reg]*adv[0] + acc[1][reg]*adv[1] + acc[2][reg]*adv[2] + acc[3][reg]*adv[3];
#pragma unroll
        for (int ofs = 1; ofs < 16; ofs <<= 1) {
            s += __shfl_xor(s, ofs);
            d += __shfl_xor(d, ofs);
        }
        if (ok && q == 0) { as2[n] = s; ad2[n] = d; }
    }
}

// ---------------------------------------------------------------------------
// gather2: fused softmax + aggregate + bias, full-row. ONE DST PER 16-LANE
// GROUP (lane j2 owns positions j2*4..+4 = ushort4 8B; 16 lanes = 128B row).
// 4 dst/wave, 4x unroll, zero reductions. Writes d_out (un-permuting C2).
// ---------------------------------------------------------------------------
__global__ __launch_bounds__(256) void k_gather2(
    const unsigned short* __restrict__ esrc, const int* __restrict__ off,
    const float* __restrict__ as2, const float* __restrict__ ad2,
    const unsigned short* __restrict__ h2b, const float* __restrict__ b2,
    float* __restrict__ out)
{
    const int t = threadIdx.x;
    const int w = t >> 6;
    const int lane = t & 63;
    const int g  = lane >> 4;                       // dst group
    const int j2 = lane & 15;                       // col-lane
    const int d = blockIdx.x * 16 + w * 4 + g;      // 3125*16 = 50000 exact
    const float adv = ad2[d];
    const int e0 = off[d], e1 = off[d + 1];
    const unsigned short* hb = h2b + j2 * 4;

    float acc[4] = {0.f, 0.f, 0.f, 0.f};
    float dn = 0.f;
    int e = e0;
    for (; e + 3 < e1; e += 4) {
        int s0 = esrc[e], s1 = esrc[e + 1], s2 = esrc[e + 2], s3 = esrc[e + 3];
        float w0 = __expf(lrelu(as2[s0] + adv));
        float w1 = __expf(lrelu(as2[s1] + adv));
        float w2 = __expf(lrelu(as2[s2] + adv));
        float w3 = __expf(lrelu(as2[s3] + adv));
        ushort4 u0 = *(const ushort4*)(hb + s0 * 64);
        ushort4 u1 = *(const ushort4*)(hb + s1 * 64);
        ushort4 u2 = *(const ushort4*)(hb + s2 * 64);
        ushort4 u3 = *(const ushort4*)(hb + s3 * 64);
        dn += (w0 + w1) + (w2 + w3);
        acc[0] = fmaf(w0, bf2f(u0.x), fmaf(w1, bf2f(u1.x), fmaf(w2, bf2f(u2.x), fmaf(w3, bf2f(u3.x), acc[0]))));
        acc[1] = fmaf(w0, bf2f(u0.y), fmaf(w1, bf2f(u1.y), fmaf(w2, bf2f(u2.y), fmaf(w3, bf2f(u3.y), acc[1]))));
        acc[2] = fmaf(w0, bf2f(u0.z), fmaf(w1, bf2f(u1.z), fmaf(w2, bf2f(u2.z), fmaf(w3, bf2f(u3.z), acc[2]))));
        acc[3] = fmaf(w0, bf2f(u0.w), fmaf(w1, bf2f(u1.w), fmaf(w2, bf2f(u2.w), fmaf(w3, bf2f(u3.w), acc[3]))));
    }
    for (; e < e1; ++e) {
        int s0 = esrc[e];
        float w0 = __expf(lrelu(as2[s0] + adv));
        ushort4 u0 = *(const ushort4*)(hb + s0 * 64);
        dn += w0;
        acc[0] = fmaf(w0, bf2f(u0.x), acc[0]);
        acc[1] = fmaf(w0, bf2f(u0.y), acc[1]);
        acc[2] = fmaf(w0, bf2f(u0.z), acc[2]);
        acc[3] = fmaf(w0, bf2f(u0.w), acc[3]);
    }
    const float inv = 1.f / (dn + 1e-16f);
#pragma unroll
    for (int i = 0; i < 4; ++i) {
        int col = i * 16 + j2;                      // C2(j2*4+i)
        out[d * 64 + col] = acc[i] * inv + b2[col];
    }
}

// ---------------------------------------------------------------------------
// Workspace layout (bytes), total ~55.7 MB:
//   counts @ 0            200,000  [zeroed]
//   cursor @ 200,000      200,000  [zeroed]
//   off    @ 400,000      200,004
//   bsum   @ 600,064      800
//   as1    @ 600,896      800,000
//   ad1    @ 1,400,896    800,000
//   as2    @ 2,200,896    200,000
//   ad2    @ 2,400,896    200,000
//   esrc   @ 2,600,896    1,700,000  uint16
//   Wf1    @ 4,300,896    131,072
//   Wf2    @ 4,431,968    32,768
//   h1b    @ 4,464,736    25,600,000 bf16 C1-perm (h2b reuses after gather1)
//   h2b    @ 4,464,736    6,400,000  bf16 C2-perm
//   hmid   @ 30,064,736   25,600,000 bf16 C1-perm
// ---------------------------------------------------------------------------
extern "C" void kernel_launch(void* const* d_in, const int* in_sizes, int n_in,
                              void* d_out, int out_size, void* d_ws, size_t ws_size,
                              hipStream_t stream)
{
    const float* x        = (const float*)d_in[0];
    const int*   ei       = (const int*)d_in[1];
    const float* W1       = (const float*)d_in[2];
    const float* att_src1 = (const float*)d_in[3];
    const float* att_dst1 = (const float*)d_in[4];
    const float* b1       = (const float*)d_in[5];
    const float* W2       = (const float*)d_in[6];
    const float* att_src2 = (const float*)d_in[7];
    const float* att_dst2 = (const float*)d_in[8];
    const float* b2       = (const float*)d_in[9];
    const int* src = ei;
    const int* dst = ei + E_RAW;
    float* out = (float*)d_out;

    char* ws = (char*)d_ws;
    int*            counts = (int*)(ws + 0);
    int*            cursor = (int*)(ws + 200000);
    int*            off    = (int*)(ws + 400000);
    int*            bsum   = (int*)(ws + 600064);
    float*          as1    = (float*)(ws + 600896);
    float*          ad1    = (float*)(ws + 1400896);
    float*          as2    = (float*)(ws + 2200896);
    float*          ad2    = (float*)(ws + 2400896);
    unsigned short* esrc   = (unsigned short*)(ws + 2600896);
    unsigned short* Wf1    = (unsigned short*)(ws + 4300896);
    unsigned short* Wf2    = (unsigned short*)(ws + 4431968);
    unsigned short* h1b    = (unsigned short*)(ws + 4464736);
    unsigned short* h2b    = (unsigned short*)(ws + 4464736);   // reuses h1b
    unsigned short* hmid   = (unsigned short*)(ws + 30064736);

    hipMemsetAsync(ws, 0, 400000, stream);      // counts + cursor

    const int EB = (E_TOT + 255) / 256;
    k_prepw  <<<40, 256, 0, stream>>>(W1, W2, Wf1, Wf2);
    k_hist   <<<EB, 256, 0, stream>>>(dst, counts);
    k_scan1  <<<NBC, 256, 0, stream>>>(counts, off, bsum);
    k_scan2  <<<1, 256, 0, stream>>>(bsum);
    k_scan3  <<<NBC, 256, 0, stream>>>(off, bsum);
    k_scatter<<<EB, 256, 0, stream>>>(src, dst, off, cursor, esrc);

    k_gemm1  <<<3125, 256, 0, stream>>>(x, Wf1, att_src1, att_dst1, h1b, as1, ad1);
    k_gather1<<<6250, 256, 0, stream>>>(esrc, off, as1, ad1, h1b, b1, hmid);
    k_gemm2  <<<782, 256, 0, stream>>>(hmid, Wf2, att_src2, att_dst2, h2b, as2, ad2);
    k_gather2<<<3125, 256, 0, stream>>>(esrc, off, as2, ad2, h2b, b2, out);
}

// Round 9
// 249.070 us; speedup vs baseline: 1.9384x; 1.0247x over previous
//
#include <hip/hip_runtime.h>
#include <math.h>

#define N_NODES 50000
#define E_RAW   800000
#define E_TOT   850000
#define NEG_SLOPE 0.2f
#define NBC 196   // scan blocks = ceil(50000/256)

typedef __attribute__((ext_vector_type(8))) short short8;
typedef __attribute__((ext_vector_type(4))) float f32x4;

__device__ __forceinline__ float lrelu(float v) {
    return v >= 0.f ? v : NEG_SLOPE * v;
}
__device__ __forceinline__ unsigned short f2bf(float f) {
    union { float f; unsigned u; } v; v.f = f;
    unsigned r = v.u + 0x7FFF + ((v.u >> 16) & 1);
    return (unsigned short)(r >> 16);
}
__device__ __forceinline__ float bf2f(unsigned short h) {
    union { unsigned u; float f; } v; v.u = ((unsigned)h) << 16;
    return v.f;
}
// h1b/hmid position p holds column C1(p) (16x16 transpose, self-inverse)
__device__ __forceinline__ int C1(int p) { return (p & 15) * 16 + (p >> 4); }
// h2b position p holds column C2(p)
__device__ __forceinline__ int C2(int p) { return (p & 3) * 16 + (p >> 2); }

// ---------------------------------------------------------------------------
// prep (weight frags) + histogram, fused. Blocks 0..39 also do weight prep.
// ---------------------------------------------------------------------------
__global__ __launch_bounds__(256) void k_prep_hist(
    const int* __restrict__ dst, int* __restrict__ counts,
    const float* __restrict__ W1, const float* __restrict__ W2,
    unsigned short* __restrict__ Wf1, unsigned short* __restrict__ Wf2)
{
    int idx = blockIdx.x * 256 + threadIdx.x;
    if (idx < 8192) {
        int lane = idx & 63, kb = (idx >> 6) & 7, nb = idx >> 9;
        int c = nb * 16 + (lane & 15);
        int k0 = kb * 32 + ((lane >> 4) & 3) * 8;
        short8 pk;
#pragma unroll
        for (int j = 0; j < 8; ++j)
            pk[j] = (short)f2bf(W1[(k0 + j) * 256 + c]);
        *(short8*)&Wf1[idx * 8] = pk;
    } else if (idx < 10240) {
        int i2 = idx - 8192;
        int lane = i2 & 63, kb = (i2 >> 6) & 7, nb = i2 >> 9;
        int c = nb * 16 + (lane & 15);
        int k0 = kb * 32 + ((lane >> 4) & 3) * 8;
        short8 pk;
#pragma unroll
        for (int j = 0; j < 8; ++j)
            pk[j] = (short)f2bf(W2[C1(k0 + j) * 64 + c]);
        *(short8*)&Wf2[i2 * 8] = pk;
    }
    if (idx < E_TOT) {
        int d = (idx < E_RAW) ? dst[idx] : idx - E_RAW;
        atomicAdd(&counts[d], 1);
    }
}

__global__ __launch_bounds__(256) void k_scan1(
    const int* __restrict__ counts, int* __restrict__ off, int* __restrict__ bsum)
{
    __shared__ int sh[256];
    int t = threadIdx.x, i = blockIdx.x * 256 + t;
    int c = (i < N_NODES) ? counts[i] : 0;
    sh[t] = c; __syncthreads();
    for (int ofs = 1; ofs < 256; ofs <<= 1) {
        int v = (t >= ofs) ? sh[t - ofs] : 0;
        __syncthreads(); sh[t] += v; __syncthreads();
    }
    if (i < N_NODES) off[i] = sh[t] - c;
    if (t == 255) bsum[blockIdx.x] = sh[255];
}

__global__ __launch_bounds__(256) void k_scan2(int* __restrict__ bsum)
{
    __shared__ int sh[256];
    int t = threadIdx.x;
    int c = (t < NBC) ? bsum[t] : 0;
    sh[t] = c; __syncthreads();
    for (int ofs = 1; ofs < 256; ofs <<= 1) {
        int v = (t >= ofs) ? sh[t - ofs] : 0;
        __syncthreads(); sh[t] += v; __syncthreads();
    }
    if (t < NBC) bsum[t] = sh[t] - c;
}

__global__ __launch_bounds__(256) void k_scan3(
    int* __restrict__ off, const int* __restrict__ bsum)
{
    int i = blockIdx.x * 256 + threadIdx.x;
    if (i < N_NODES) off[i] += bsum[blockIdx.x];
    if (i == 0) off[N_NODES] = E_TOT;
}

// ---------------------------------------------------------------------------
// scatter + layer-1 edge weights. Runs AFTER gemm1 (needs as1/ad1).
// Per edge: CSR position, esrc (uint16), and the 4 head-weights
// w_h = exp(lrelu(as1[s,h]+ad1[d,h])) as one float4 store at aw1[pos].
// ---------------------------------------------------------------------------
__global__ __launch_bounds__(256) void k_scatter(
    const int* __restrict__ src, const int* __restrict__ dst,
    const int* __restrict__ off, int* __restrict__ cursor,
    const float* __restrict__ as1, const float* __restrict__ ad1,
    unsigned short* __restrict__ esrc, float* __restrict__ aw1)
{
    int e = blockIdx.x * 256 + threadIdx.x;
    if (e >= E_TOT) return;
    int s, d;
    if (e < E_RAW) { s = src[e]; d = dst[e]; } else { s = e - E_RAW; d = s; }
    int pos = off[d] + atomicAdd(&cursor[d], 1);
    esrc[pos] = (unsigned short)s;
    float4 A = *(const float4*)&as1[s * 4];
    float4 B = *(const float4*)&ad1[d * 4];
    float4 w;
    w.x = __expf(lrelu(A.x + B.x));
    w.y = __expf(lrelu(A.y + B.y));
    w.z = __expf(lrelu(A.z + B.z));
    w.w = __expf(lrelu(A.w + B.w));
    *(float4*)&aw1[pos * 4] = w;
}

// ---------------------------------------------------------------------------
// GEMM1: h1 = x @ W1, MFMA 16x16x32. 3125 blocks x 4 waves, 16 rows/block,
// wave w = head w. Register double-buffer. h1b stored C1-PERMUTED (8B
// ushort4 stores). Fused att-dot epilogue.
// ---------------------------------------------------------------------------
__global__ __launch_bounds__(256) void k_gemm1(
    const float* __restrict__ x, const unsigned short* __restrict__ Wf1,
    const float* __restrict__ att_src, const float* __restrict__ att_dst,
    unsigned short* __restrict__ h1b, float* __restrict__ as1, float* __restrict__ ad1)
{
    const int t = threadIdx.x;
    const int lane = t & 63;
    const int w = t >> 6;
    const int rbase = blockIdx.x * 16;
    const int q  = lane & 15;
    const int kg = lane >> 4;
    const int rowA = rbase + q;

    f32x4 acc[4];
#pragma unroll
    for (int nb = 0; nb < 4; ++nb) acc[nb] = (f32x4){0.f, 0.f, 0.f, 0.f};

    short8 b[2][4];
    float4 a0, a1, a0n, a1n;
    {
        const float* ap = &x[rowA * 256 + kg * 8];
        a0 = *(const float4*)ap;
        a1 = *(const float4*)(ap + 4);
#pragma unroll
        for (int nb = 0; nb < 4; ++nb)
            b[0][nb] = *(const short8*)&Wf1[(((w * 4 + nb) * 8 + 0) * 64 + lane) * 8];
    }
#pragma unroll
    for (int kb = 0; kb < 8; ++kb) {
        if (kb < 7) {
            const float* ap = &x[rowA * 256 + (kb + 1) * 32 + kg * 8];
            a0n = *(const float4*)ap;
            a1n = *(const float4*)(ap + 4);
#pragma unroll
            for (int nb = 0; nb < 4; ++nb)
                b[(kb + 1) & 1][nb] =
                    *(const short8*)&Wf1[(((w * 4 + nb) * 8 + kb + 1) * 64 + lane) * 8];
        }
        short8 af;
        af[0] = (short)f2bf(a0.x); af[1] = (short)f2bf(a0.y);
        af[2] = (short)f2bf(a0.z); af[3] = (short)f2bf(a0.w);
        af[4] = (short)f2bf(a1.x); af[5] = (short)f2bf(a1.y);
        af[6] = (short)f2bf(a1.z); af[7] = (short)f2bf(a1.w);
#pragma unroll
        for (int nb = 0; nb < 4; ++nb)
            acc[nb] = __builtin_amdgcn_mfma_f32_16x16x32_bf16(af, b[kb & 1][nb], acc[nb], 0, 0, 0);
        if (kb < 7) { a0 = a0n; a1 = a1n; }
    }

#pragma unroll
    for (int reg = 0; reg < 4; ++reg) {
        int n = rbase + kg * 4 + reg;
        ushort4 pk;
        pk.x = f2bf(acc[0][reg]); pk.y = f2bf(acc[1][reg]);
        pk.z = f2bf(acc[2][reg]); pk.w = f2bf(acc[3][reg]);
        *(ushort4*)&h1b[n * 256 + q * 16 + w * 4] = pk;   // C1-permuted, 8B
    }
    float asv[4], adv[4];
#pragma unroll
    for (int nb = 0; nb < 4; ++nb) {
        int col = (w * 4 + nb) * 16 + q;
        asv[nb] = att_src[col];
        adv[nb] = att_dst[col];
    }
#pragma unroll
    for (int reg = 0; reg < 4; ++reg) {
        float s = acc[0][reg]*asv[0] + acc[1][reg]*asv[1] + acc[2][reg]*asv[2] + acc[3][reg]*asv[3];
        float d = acc[0][reg]*adv[0] + acc[1][reg]*adv[1] + acc[2][reg]*adv[2] + acc[3][reg]*adv[3];
#pragma unroll
        for (int ofs = 1; ofs < 16; ofs <<= 1) {
            s += __shfl_xor(s, ofs);
            d += __shfl_xor(d, ofs);
        }
        if (q == 0) {
            int n = rbase + kg * 4 + reg;
            as1[n * 4 + w] = s;
            ad1[n * 4 + w] = d;
        }
    }
}

// ---------------------------------------------------------------------------
// gather1: r5-proven structure — wave per dst, lane owns C1-positions
// lane*4..+3 (head = lane&3), 4x unroll. Inner loop now pure loads+fma:
// precomputed f32 weight aw1[e*4+head] (broadcast within 16-lane group).
// Denominator accumulated per-lane in f32, same order as round 5.
// ---------------------------------------------------------------------------
__global__ __launch_bounds__(256) void k_gather1(
    const unsigned short* __restrict__ esrc, const int* __restrict__ off,
    const float* __restrict__ aw1,
    const unsigned short* __restrict__ h1b, const float* __restrict__ b1,
    unsigned short* __restrict__ hmid)
{
    int d    = (blockIdx.x * 256 + threadIdx.x) >> 6;   // 12500*4 = 50000 exact
    int lane = threadIdx.x & 63;
    const int head = lane & 3;
    const int e0 = off[d], e1 = off[d + 1];
    float4 acc = make_float4(0.f, 0.f, 0.f, 0.f);
    float dn = 0.f;
    int e = e0;
    for (; e + 3 < e1; e += 4) {
        int s0 = esrc[e], s1 = esrc[e + 1], s2 = esrc[e + 2], s3 = esrc[e + 3];
        float w0 = aw1[(e + 0) * 4 + head];
        float w1 = aw1[(e + 1) * 4 + head];
        float w2 = aw1[(e + 2) * 4 + head];
        float w3 = aw1[(e + 3) * 4 + head];
        ushort4 u0 = *(const ushort4*)&h1b[s0 * 256 + lane * 4];
        ushort4 u1 = *(const ushort4*)&h1b[s1 * 256 + lane * 4];
        ushort4 u2 = *(const ushort4*)&h1b[s2 * 256 + lane * 4];
        ushort4 u3 = *(const ushort4*)&h1b[s3 * 256 + lane * 4];
        dn += (w0 + w1) + (w2 + w3);
        acc.x = fmaf(w0, bf2f(u0.x), fmaf(w1, bf2f(u1.x), fmaf(w2, bf2f(u2.x), fmaf(w3, bf2f(u3.x), acc.x))));
        acc.y = fmaf(w0, bf2f(u0.y), fmaf(w1, bf2f(u1.y), fmaf(w2, bf2f(u2.y), fmaf(w3, bf2f(u3.y), acc.y))));
        acc.z = fmaf(w0, bf2f(u0.z), fmaf(w1, bf2f(u1.z), fmaf(w2, bf2f(u2.z), fmaf(w3, bf2f(u3.z), acc.z))));
        acc.w = fmaf(w0, bf2f(u0.w), fmaf(w1, bf2f(u1.w), fmaf(w2, bf2f(u2.w), fmaf(w3, bf2f(u3.w), acc.w))));
    }
    for (; e < e1; ++e) {
        int s0 = esrc[e];
        float w0 = aw1[e * 4 + head];
        ushort4 u0 = *(const ushort4*)&h1b[s0 * 256 + lane * 4];
        dn += w0;
        acc.x = fmaf(w0, bf2f(u0.x), acc.x);
        acc.y = fmaf(w0, bf2f(u0.y), acc.y);
        acc.z = fmaf(w0, bf2f(u0.z), acc.z);
        acc.w = fmaf(w0, bf2f(u0.w), acc.w);
    }
    const float inv = 1.f / (dn + 1e-16f);
    float o[4] = {acc.x, acc.y, acc.z, acc.w};
    ushort4 pk;
    unsigned short* pko = (unsigned short*)&pk;
#pragma unroll
    for (int i = 0; i < 4; ++i) {
        float v = o[i] * inv + b1[C1(lane * 4 + i)];
        v = v > 0.f ? v : expm1f(v);
        pko[i] = f2bf(v);
    }
    *(ushort4*)&hmid[d * 256 + lane * 4] = pk;          // C1-permuted, 8B
}

// ---------------------------------------------------------------------------
// GEMM2: h2 = hmid @ W2 (hmid C1-permuted; Wf2 compensates). Register
// double-buffer; h2b stored C2-permuted (ushort4 8B); fused att2 epilogue.
// ---------------------------------------------------------------------------
__global__ __launch_bounds__(256) void k_gemm2(
    const unsigned short* __restrict__ hmid, const unsigned short* __restrict__ Wf2,
    const float* __restrict__ att_src, const float* __restrict__ att_dst,
    unsigned short* __restrict__ h2b, float* __restrict__ as2, float* __restrict__ ad2)
{
    const int t = threadIdx.x;
    const int lane = t & 63;
    const int w = t >> 6;
    const int rbase = blockIdx.x * 64 + w * 16;
    const int q  = lane & 15;
    const int kg = lane >> 4;
    const int rowA = rbase + q;
    const int rA = rowA < N_NODES ? rowA : N_NODES - 1;

    f32x4 acc[4];
#pragma unroll
    for (int nb = 0; nb < 4; ++nb) acc[nb] = (f32x4){0.f, 0.f, 0.f, 0.f};

    short8 b[2][4];
    short8 af, afn;
    af = *(const short8*)&hmid[rA * 256 + kg * 8];
#pragma unroll
    for (int nb = 0; nb < 4; ++nb)
        b[0][nb] = *(const short8*)&Wf2[((nb * 8 + 0) * 64 + lane) * 8];
#pragma unroll
    for (int kb = 0; kb < 8; ++kb) {
        if (kb < 7) {
            afn = *(const short8*)&hmid[rA * 256 + (kb + 1) * 32 + kg * 8];
#pragma unroll
            for (int nb = 0; nb < 4; ++nb)
                b[(kb + 1) & 1][nb] = *(const short8*)&Wf2[((nb * 8 + kb + 1) * 64 + lane) * 8];
        }
#pragma unroll
        for (int nb = 0; nb < 4; ++nb)
            acc[nb] = __builtin_amdgcn_mfma_f32_16x16x32_bf16(af, b[kb & 1][nb], acc[nb], 0, 0, 0);
        if (kb < 7) af = afn;
    }

    float asv[4], adv[4];
#pragma unroll
    for (int nb = 0; nb < 4; ++nb) {
        int col = nb * 16 + q;
        asv[nb] = att_src[col];
        adv[nb] = att_dst[col];
    }
#pragma unroll
    for (int reg = 0; reg < 4; ++reg) {
        int n = rbase + kg * 4 + reg;
        bool ok = n < N_NODES;
        if (ok) {
            ushort4 pk;
            pk.x = f2bf(acc[0][reg]); pk.y = f2bf(acc[1][reg]);
            pk.z = f2bf(acc[2][reg]); pk.w = f2bf(acc[3][reg]);
            *(ushort4*)&h2b[n * 64 + q * 4] = pk;   // position q*4+nb = col nb*16+q
        }
        float s = acc[0][reg]*asv[0] + acc[1][reg]*asv[1] + acc[2][reg]*asv[2] + acc[3][reg]*asv[3];
        float d = acc[0][reg]*adv[0] + acc[1][reg]*adv[1] + acc[2][reg]*adv[2] + acc[3][reg]*adv[3];
#pragma unroll
        for (int ofs = 1; ofs < 16; ofs <<= 1) {
            s += __shfl_xor(s, ofs);
            d += __shfl_xor(d, ofs);
        }
        if (ok && q == 0) { as2[n] = s; ad2[n] = d; }
    }
}

// ---------------------------------------------------------------------------
// gather2: 4 dst per wave (16-lane group owns ushort4 = 128B row), 4x unroll,
// inline exp (cheap here: 1 exp per 4 edges per wave-inst). Writes d_out.
// ---------------------------------------------------------------------------
__global__ __launch_bounds__(256) void k_gather2(
    const unsigned short* __restrict__ esrc, const int* __restrict__ off,
    const float* __restrict__ as2, const float* __restrict__ ad2,
    const unsigned short* __restrict__ h2b, const float* __restrict__ b2,
    float* __restrict__ out)
{
    const int t = threadIdx.x;
    const int w = t >> 6;
    const int lane = t & 63;
    const int g  = lane >> 4;
    const int j2 = lane & 15;
    const int d = blockIdx.x * 16 + w * 4 + g;      // 3125*16 = 50000 exact
    const float adv = ad2[d];
    const int e0 = off[d], e1 = off[d + 1];
    const unsigned short* hb = h2b + j2 * 4;

    float acc[4] = {0.f, 0.f, 0.f, 0.f};
    float dn = 0.f;
    int e = e0;
    for (; e + 3 < e1; e += 4) {
        int s0 = esrc[e], s1 = esrc[e + 1], s2 = esrc[e + 2], s3 = esrc[e + 3];
        float w0 = __expf(lrelu(as2[s0] + adv));
        float w1 = __expf(lrelu(as2[s1] + adv));
        float w2 = __expf(lrelu(as2[s2] + adv));
        float w3 = __expf(lrelu(as2[s3] + adv));
        ushort4 u0 = *(const ushort4*)(hb + s0 * 64);
        ushort4 u1 = *(const ushort4*)(hb + s1 * 64);
        ushort4 u2 = *(const ushort4*)(hb + s2 * 64);
        ushort4 u3 = *(const ushort4*)(hb + s3 * 64);
        dn += (w0 + w1) + (w2 + w3);
        acc[0] = fmaf(w0, bf2f(u0.x), fmaf(w1, bf2f(u1.x), fmaf(w2, bf2f(u2.x), fmaf(w3, bf2f(u3.x), acc[0]))));
        acc[1] = fmaf(w0, bf2f(u0.y), fmaf(w1, bf2f(u1.y), fmaf(w2, bf2f(u2.y), fmaf(w3, bf2f(u3.y), acc[1]))));
        acc[2] = fmaf(w0, bf2f(u0.z), fmaf(w1, bf2f(u1.z), fmaf(w2, bf2f(u2.z), fmaf(w3, bf2f(u3.z), acc[2]))));
        acc[3] = fmaf(w0, bf2f(u0.w), fmaf(w1, bf2f(u1.w), fmaf(w2, bf2f(u2.w), fmaf(w3, bf2f(u3.w), acc[3]))));
    }
    for (; e < e1; ++e) {
        int s0 = esrc[e];
        float w0 = __expf(lrelu(as2[s0] + adv));
        ushort4 u0 = *(const ushort4*)(hb + s0 * 64);
        dn += w0;
        acc[0] = fmaf(w0, bf2f(u0.x), acc[0]);
        acc[1] = fmaf(w0, bf2f(u0.y), acc[1]);
        acc[2] = fmaf(w0, bf2f(u0.z), acc[2]);
        acc[3] = fmaf(w0, bf2f(u0.w), acc[3]);
    }
    const float inv = 1.f / (dn + 1e-16f);
#pragma unroll
    for (int i = 0; i < 4; ++i) {
        int col = i * 16 + j2;                      // C2(j2*4+i)
        out[d * 64 + col] = acc[i] * inv + b2[col];
    }
}

// ---------------------------------------------------------------------------
// Workspace layout (bytes), total ~72.7 MB:
//   counts @ 0            200,000  [zeroed]
//   cursor @ 200,000      200,000  [zeroed]
//   off    @ 400,000      200,004
//   bsum   @ 600,064      800
//   as1    @ 600,896      800,000
//   ad1    @ 1,400,896    800,000
//   as2    @ 2,200,896    200,000
//   ad2    @ 2,400,896    200,000
//   esrc   @ 2,600,896    1,700,000  uint16
//   Wf1    @ 4,300,896    131,072
//   Wf2    @ 4,431,968    32,768
//   aw1    @ 4,464,736    13,600,000 f32 x4 heads, CSR order
//   h1b    @ 18,064,736   25,600,000 bf16 C1-perm (h2b reuses after gather1)
//   h2b    @ 18,064,736   6,400,000  bf16 C2-perm
//   hmid   @ 43,664,736   25,600,000 bf16 C1-perm
// ---------------------------------------------------------------------------
extern "C" void kernel_launch(void* const* d_in, const int* in_sizes, int n_in,
                              void* d_out, int out_size, void* d_ws, size_t ws_size,
                              hipStream_t stream)
{
    const float* x        = (const float*)d_in[0];
    const int*   ei       = (const int*)d_in[1];
    const float* W1       = (const float*)d_in[2];
    const float* att_src1 = (const float*)d_in[3];
    const float* att_dst1 = (const float*)d_in[4];
    const float* b1       = (const float*)d_in[5];
    const float* W2       = (const float*)d_in[6];
    const float* att_src2 = (const float*)d_in[7];
    const float* att_dst2 = (const float*)d_in[8];
    const float* b2       = (const float*)d_in[9];
    const int* src = ei;
    const int* dst = ei + E_RAW;
    float* out = (float*)d_out;

    char* ws = (char*)d_ws;
    int*            counts = (int*)(ws + 0);
    int*            cursor = (int*)(ws + 200000);
    int*            off    = (int*)(ws + 400000);
    int*            bsum   = (int*)(ws + 600064);
    float*          as1    = (float*)(ws + 600896);
    float*          ad1    = (float*)(ws + 1400896);
    float*          as2    = (float*)(ws + 2200896);
    float*          ad2    = (float*)(ws + 2400896);
    unsigned short* esrc   = (unsigned short*)(ws + 2600896);
    unsigned short* Wf1    = (unsigned short*)(ws + 4300896);
    unsigned short* Wf2    = (unsigned short*)(ws + 4431968);
    float*          aw1    = (float*)(ws + 4464736);
    unsigned short* h1b    = (unsigned short*)(ws + 18064736);
    unsigned short* h2b    = (unsigned short*)(ws + 18064736);  // reuses h1b
    unsigned short* hmid   = (unsigned short*)(ws + 43664736);

    hipMemsetAsync(ws, 0, 400000, stream);      // counts + cursor

    const int EB = (E_TOT + 255) / 256;
    k_prep_hist<<<EB, 256, 0, stream>>>(dst, counts, W1, W2, Wf1, Wf2);
    k_scan1  <<<NBC, 256, 0, stream>>>(counts, off, bsum);
    k_scan2  <<<1, 256, 0, stream>>>(bsum);
    k_scan3  <<<NBC, 256, 0, stream>>>(off, bsum);
    k_gemm1  <<<3125, 256, 0, stream>>>(x, Wf1, att_src1, att_dst1, h1b, as1, ad1);
    k_scatter<<<EB, 256, 0, stream>>>(src, dst, off, cursor, as1, ad1, esrc, aw1);
    k_gather1<<<12500, 256, 0, stream>>>(esrc, off, aw1, h1b, b1, hmid);
    k_gemm2  <<<782, 256, 0, stream>>>(hmid, Wf2, att_src2, att_dst2, h2b, as2, ad2);
    k_gather2<<<3125, 256, 0, stream>>>(esrc, off, as2, ad2, h2b, b2, out);
}